// Round 5
// baseline (56.209 us; speedup 1.0000x reference)
//
#include <hip/hip_runtime.h>

#define NB 8
#define C_OUT 64
#define NK 11
#define HH 64
#define WW 64
#define NG 4
#define HW (HH*WW)
#define CH (C_OUT*NK)
#define SPLIT 4          // strips per (b,r) tile; 16 rows each

typedef float f32x4 __attribute__((ext_vector_type(4)));

__global__ __launch_bounds__(256, 4) void fused_addshift_kernel(
    const float* __restrict__ x,
    const int* __restrict__ perm_h,
    const int* __restrict__ perm_v,
    const int* __restrict__ sel_id,
    float* __restrict__ out)
{
    const int blk = blockIdx.x;          // ((b*C_OUT + r) * SPLIT) + strip
    const int strip = blk & (SPLIT - 1);
    const int br = blk >> 2;
    const int b = br >> 6;
    const int r = br & 63;

    __shared__ float c1[3][NK];
    __shared__ float c2[3][NK];
    __shared__ float cs[NK];
    __shared__ int ic1[3][NK], ic2[3][NK], ics[NK];

    const int tid = threadIdx.x;

    if (tid < 33) { ic1[tid / 11][tid % 11] = 0; ic2[tid / 11][tid % 11] = 0; }
    if (tid >= 33 && tid < 44) ics[tid - 33] = 0;
    __syncthreads();

    if (tid < 44) {
        int g = tid / 11, k = tid % 11;
        int m = (r * NK + k) % 3;
        int j1 = perm_h[(g * C_OUT + r) * NK + k] % NK;
        int j2 = perm_v[(g * C_OUT + r) * NK + k] % NK;
        atomicAdd(&ic1[m][j1], 1);
        atomicAdd(&ic2[m][j2], 1);
    } else if (tid < 48) {
        int g = tid - 44;
        int j = sel_id[g * C_OUT + r] % NK;
        atomicAdd(&ics[j], 1);
    }
    __syncthreads();
    if (tid < 33) {
        c1[tid / 11][tid % 11] = (float)ic1[tid / 11][tid % 11];
        c2[tid / 11][tid % 11] = (float)ic2[tid / 11][tid % 11];
    }
    if (tid >= 33 && tid < 44) cs[tid - 33] = (float)ics[tid - 33];
    __syncthreads();

    const float* xp = x + ((size_t)b * CH + (size_t)r * NK) * HW;
    float* o1 = out + ((size_t)b * C_OUT + r) * HW;
    float* o2 = o1 + (size_t)NB * C_OUT * HW;
    float* o3 = o2 + (size_t)NB * C_OUT * HW;

    // thread -> one float4: 16 threads per row, 16 rows per strip
    const int row_local = tid >> 4;            // 0..15
    const int w4 = (tid & 15) << 2;            // 0,4,...,60
    const int h   = strip * 16 + row_local;
    const int hm1 = (h + HH - 1) & (HH - 1);
    const int hm2 = (h + HH - 2) & (HH - 1);

    // left neighbor within the 16-lane row group (wraps w4=0 -> w4=60)
    const int lane = tid & 63;
    const int srcLane = (lane & 48) | ((lane + 15) & 15);

    f32x4 acc1 = {0.f, 0.f, 0.f, 0.f};
    f32x4 acc2 = {0.f, 0.f, 0.f, 0.f};
    f32x4 accs = {0.f, 0.f, 0.f, 0.f};

    #pragma unroll
    for (int j = 0; j < NK; ++j) {
        const float* cp = xp + j * HW;
        const f32x4 X0 = *reinterpret_cast<const f32x4*>(cp + h   * WW + w4);
        const f32x4 a1 = *reinterpret_cast<const f32x4*>(cp + hm1 * WW + w4);
        const f32x4 b1 = *reinterpret_cast<const f32x4*>(cp + hm2 * WW + w4);

        // left neighbor's a1.z/a1.w/b1.w supply the wrapped columns
        const float nAz = __shfl(a1.z, srcLane, 64);
        const float nAw = __shfl(a1.w, srcLane, 64);
        const float nBw = __shfl(b1.w, srcLane, 64);

        // XA = row h-1, cols w-2..w+1 ; XB = row h-2, cols w-1..w+2
        const float XAx = nAz,  XAy = nAw,  XAz = a1.x, XAw = a1.y;
        const float XBx = nBw,  XBy = b1.x, XBz = b1.y, XBw = b1.z;

        const float w10 = c1[0][j], w11 = c1[1][j], w12 = c1[2][j];
        const float w20 = c2[0][j], w21 = c2[1][j], w22 = c2[2][j];
        const float wss = cs[j];

        acc1.x = fmaf(w10, X0.x, fmaf(w11, XAx, fmaf(w12, XBx, acc1.x)));
        acc1.y = fmaf(w10, X0.y, fmaf(w11, XAy, fmaf(w12, XBy, acc1.y)));
        acc1.z = fmaf(w10, X0.z, fmaf(w11, XAz, fmaf(w12, XBz, acc1.z)));
        acc1.w = fmaf(w10, X0.w, fmaf(w11, XAw, fmaf(w12, XBw, acc1.w)));

        acc2.x = fmaf(w20, X0.x, fmaf(w21, XBx, fmaf(w22, XAx, acc2.x)));
        acc2.y = fmaf(w20, X0.y, fmaf(w21, XBy, fmaf(w22, XAy, acc2.y)));
        acc2.z = fmaf(w20, X0.z, fmaf(w21, XBz, fmaf(w22, XAz, acc2.z)));
        acc2.w = fmaf(w20, X0.w, fmaf(w21, XBw, fmaf(w22, XAw, acc2.w)));

        accs.x = fmaf(wss, X0.x, accs.x);
        accs.y = fmaf(wss, X0.y, accs.y);
        accs.z = fmaf(wss, X0.z, accs.z);
        accs.w = fmaf(wss, X0.w, accs.w);
    }

    const int idx = h * WW + w4;
    *reinterpret_cast<f32x4*>(o1 + idx) = acc1;
    *reinterpret_cast<f32x4*>(o2 + idx) = acc2;
    *reinterpret_cast<f32x4*>(o3 + idx) = accs;
}

extern "C" void kernel_launch(void* const* d_in, const int* in_sizes, int n_in,
                              void* d_out, int out_size, void* d_ws, size_t ws_size,
                              hipStream_t stream) {
    const float* x      = (const float*)d_in[0];
    const int* perm_h   = (const int*)d_in[1];
    const int* perm_v   = (const int*)d_in[2];
    const int* sel_id   = (const int*)d_in[3];
    float* out          = (float*)d_out;

    dim3 grid(NB * C_OUT * SPLIT);
    dim3 block(256);
    hipLaunchKernelGGL(fused_addshift_kernel, grid, block, 0, stream,
                       x, perm_h, perm_v, sel_id, out);
}

// Round 6
// 29.203 us; speedup vs baseline: 1.9248x; 1.9248x over previous
//
#include <hip/hip_runtime.h>

#define NB 8
#define C_OUT 64
#define NK 11
#define HH 64
#define WW 64
#define NG 4
#define HW (HH*WW)
#define CH (C_OUT*NK)
#define SPLIT 4          // strips per (b,r) tile; 16 rows each

typedef float f32x4 __attribute__((ext_vector_type(4)));

__global__ __launch_bounds__(256) void fused_addshift_kernel(
    const float* __restrict__ x,
    const int* __restrict__ perm_h,
    const int* __restrict__ perm_v,
    const int* __restrict__ sel_id,
    float* __restrict__ out)
{
    const int blk = blockIdx.x;          // ((b*C_OUT + r) * SPLIT) + strip
    const int strip = blk & (SPLIT - 1);
    const int br = blk >> 2;
    const int b = br >> 6;
    const int r = br & 63;

    __shared__ float c1[3][NK];
    __shared__ float c2[3][NK];
    __shared__ float cs[NK];
    __shared__ int ic1[3][NK], ic2[3][NK], ics[NK];

    const int tid = threadIdx.x;

    if (tid < 33) { ic1[tid / 11][tid % 11] = 0; ic2[tid / 11][tid % 11] = 0; }
    if (tid >= 33 && tid < 44) ics[tid - 33] = 0;
    __syncthreads();

    if (tid < 44) {
        int g = tid / 11, k = tid % 11;
        int m = (r * NK + k) % 3;
        int j1 = perm_h[(g * C_OUT + r) * NK + k] % NK;
        int j2 = perm_v[(g * C_OUT + r) * NK + k] % NK;
        atomicAdd(&ic1[m][j1], 1);
        atomicAdd(&ic2[m][j2], 1);
    } else if (tid < 48) {
        int g = tid - 44;
        int j = sel_id[g * C_OUT + r] % NK;
        atomicAdd(&ics[j], 1);
    }
    __syncthreads();
    if (tid < 33) {
        c1[tid / 11][tid % 11] = (float)ic1[tid / 11][tid % 11];
        c2[tid / 11][tid % 11] = (float)ic2[tid / 11][tid % 11];
    }
    if (tid >= 33 && tid < 44) cs[tid - 33] = (float)ics[tid - 33];
    __syncthreads();

    const float* xp = x + ((size_t)b * CH + (size_t)r * NK) * HW;
    float* o1 = out + ((size_t)b * C_OUT + r) * HW;
    float* o2 = o1 + (size_t)NB * C_OUT * HW;
    float* o3 = o2 + (size_t)NB * C_OUT * HW;

    // thread -> one float4: 16 threads per row, 16 rows per strip
    const int row_local = tid >> 4;            // 0..15
    const int w4 = (tid & 15) << 2;            // 0,4,...,60
    const int h   = strip * 16 + row_local;
    const int hm1 = (h + HH - 1) & (HH - 1);
    const int hm2 = (h + HH - 2) & (HH - 1);

    // left neighbor within the 16-lane row group (wraps w4=0 -> w4=60)
    const int lane = tid & 63;
    const int srcLane = (lane & 48) | ((lane + 15) & 15);

    f32x4 acc1 = {0.f, 0.f, 0.f, 0.f};
    f32x4 acc2 = {0.f, 0.f, 0.f, 0.f};
    f32x4 accs = {0.f, 0.f, 0.f, 0.f};

    #pragma unroll
    for (int j = 0; j < NK; ++j) {
        const float* cp = xp + j * HW;
        const f32x4 X0 = *reinterpret_cast<const f32x4*>(cp + h   * WW + w4);
        const f32x4 a1 = *reinterpret_cast<const f32x4*>(cp + hm1 * WW + w4);
        const f32x4 b1 = *reinterpret_cast<const f32x4*>(cp + hm2 * WW + w4);

        // left neighbor's a1.z/a1.w/b1.w supply the wrapped columns
        const float nAz = __shfl(a1.z, srcLane, 64);
        const float nAw = __shfl(a1.w, srcLane, 64);
        const float nBw = __shfl(b1.w, srcLane, 64);

        // XA = row h-1, cols w-2..w+1 ; XB = row h-2, cols w-1..w+2
        const float XAx = nAz,  XAy = nAw,  XAz = a1.x, XAw = a1.y;
        const float XBx = nBw,  XBy = b1.x, XBz = b1.y, XBw = b1.z;

        const float w10 = c1[0][j], w11 = c1[1][j], w12 = c1[2][j];
        const float w20 = c2[0][j], w21 = c2[1][j], w22 = c2[2][j];
        const float wss = cs[j];

        acc1.x = fmaf(w10, X0.x, fmaf(w11, XAx, fmaf(w12, XBx, acc1.x)));
        acc1.y = fmaf(w10, X0.y, fmaf(w11, XAy, fmaf(w12, XBy, acc1.y)));
        acc1.z = fmaf(w10, X0.z, fmaf(w11, XAz, fmaf(w12, XBz, acc1.z)));
        acc1.w = fmaf(w10, X0.w, fmaf(w11, XAw, fmaf(w12, XBw, acc1.w)));

        acc2.x = fmaf(w20, X0.x, fmaf(w21, XBx, fmaf(w22, XAx, acc2.x)));
        acc2.y = fmaf(w20, X0.y, fmaf(w21, XBy, fmaf(w22, XAy, acc2.y)));
        acc2.z = fmaf(w20, X0.z, fmaf(w21, XBz, fmaf(w22, XAz, acc2.z)));
        acc2.w = fmaf(w20, X0.w, fmaf(w21, XBw, fmaf(w22, XAw, acc2.w)));

        accs.x = fmaf(wss, X0.x, accs.x);
        accs.y = fmaf(wss, X0.y, accs.y);
        accs.z = fmaf(wss, X0.z, accs.z);
        accs.w = fmaf(wss, X0.w, accs.w);
    }

    const int idx = h * WW + w4;
    *reinterpret_cast<f32x4*>(o1 + idx) = acc1;
    *reinterpret_cast<f32x4*>(o2 + idx) = acc2;
    *reinterpret_cast<f32x4*>(o3 + idx) = accs;
}

extern "C" void kernel_launch(void* const* d_in, const int* in_sizes, int n_in,
                              void* d_out, int out_size, void* d_ws, size_t ws_size,
                              hipStream_t stream) {
    const float* x      = (const float*)d_in[0];
    const int* perm_h   = (const int*)d_in[1];
    const int* perm_v   = (const int*)d_in[2];
    const int* sel_id   = (const int*)d_in[3];
    float* out          = (float*)d_out;

    dim3 grid(NB * C_OUT * SPLIT);
    dim3 block(256);
    hipLaunchKernelGGL(fused_addshift_kernel, grid, block, 0, stream,
                       x, perm_h, perm_v, sel_id, out);
}